// Round 7
// baseline (141.239 us; speedup 1.0000x reference)
//
#include <hip/hip_runtime.h>

// SuperPixelMeanEmbed: x = X@W.T + b (M=32, N=K=12288), then per-superpixel
// channel means. W = 604 MB f32 read once -> HBM floor ~92 us at the
// measured 6.6 TB/s streaming rate (less where L3 keeps W warm).
//
// R7: R6's gemm had a dispatch-tail: 40 KB LDS -> 4 blocks/CU -> 1024
// co-resident slots, but grid was 1536 = 1.5 waves -> ~1.3x tail overhead.
// Fix: KSPLIT=16 -> grid 3072 = exactly 3 full waves (zero tail). Pipeline
// (counted vmcnt(5) + raw barriers), swizzles, MFMA datapath unchanged.

#include <hip/hip_bf16.h>

typedef __attribute__((ext_vector_type(8))) short short8;
typedef __attribute__((ext_vector_type(4))) float f32x4;

namespace {
constexpr int BATCH = 32;
constexpr int CH    = 3;
constexpr int HWPIX = 4096;     // 64*64
constexpr int DDIM  = 12288;
constexpr int KDIM  = 12288;
constexpr int NSEG  = 196;

constexpr int ROWS = 64;        // d-rows per block (wave w owns rows w*16..+15)
constexpr int BK   = 64;        // k per LDS tile
}

__device__ __forceinline__ ushort bf16rne(float f) {
    union { float f; unsigned u; } v; v.f = f;
    const unsigned r = v.u + 0x7fffu + ((v.u >> 16) & 1u);   // round-nearest-even
    return (ushort)(r >> 16);
}

__device__ __forceinline__ void gload16(const void* g, void* l) {
    __builtin_amdgcn_global_load_lds(
        (const __attribute__((address_space(1))) void*)g,
        (__attribute__((address_space(3))) void*)l, 16, 0, 0);
}

// ---------------- X f32 -> bf16, same [b][k] layout ----------------
__global__ __launch_bounds__(256) void convert_x_kernel(
    const float* __restrict__ X, ushort* __restrict__ Xb)
{
    const int i = (blockIdx.x * 256 + threadIdx.x) * 4;
    const float4 v = *reinterpret_cast<const float4*>(X + i);
    ushort4 o;
    o.x = bf16rne(v.x); o.y = bf16rne(v.y); o.z = bf16rne(v.z); o.w = bf16rne(v.w);
    *reinterpret_cast<ushort4*>(Xb + i) = o;
}

// ---------------- MFMA skinny GEMM, split-K ----------------
// grid = (DDIM/64, KSPLIT); block 256 = 4 waves. Wave w computes the
// 16(d) x 32(batch) output tile for rows d0+w*16..+15 over its k-range.
// LDS: W tile f32 [64r][64k] (16 KB) + X tile bf16 [32b][64k] (4 KB), x2 buf.
// Both staged by global_load_lds with pre-swizzled source chunks
// (chunk ^= row&7, 16B granules); reads XOR the same -> conflict-free.
template<int KSPLIT>
__global__ __launch_bounds__(256, 4) void gemm_kernel(
    const float* __restrict__ Wg, const ushort* __restrict__ Xb,
    float* __restrict__ xpart)
{
    constexpr int KRANGE = KDIM / KSPLIT;
    constexpr int NTILE  = KRANGE / BK;

    __shared__ float  wl[2][ROWS * BK];    // 2 x 16 KB
    __shared__ ushort xl[2][BATCH * BK];   // 2 x 4 KB

    const int t    = threadIdx.x;
    const int lane = t & 63;
    const int w    = t >> 6;
    const int d0   = blockIdx.x * ROWS;
    const int kb   = blockIdx.y * KRANGE;

    // staging geometry
    const int rsub = lane >> 4;            // W: sub-row within 4-row gload group
    const int cch  = lane & 15;            // W: 16B chunk slot (16 per 256B row)
    const int xrow = w * 8 + (lane >> 3);  // X: b-row (8 rows/wave, 128B each)
    const int xch  = lane & 7;             // X: 16B chunk slot (8 per row)

    f32x4 acc[2];
#pragma unroll
    for (int nt = 0; nt < 2; ++nt) acc[nt] = (f32x4)(0.f);

#define STAGE(buf, tile)                                                     \
    {                                                                        \
        const int k0 = kb + (tile) * BK;                                     \
        _Pragma("unroll")                                                    \
        for (int i = 0; i < 4; ++i) {                                        \
            const int r  = w * 16 + i * 4 + rsub;                            \
            const int cs = cch ^ (r & 7);                                    \
            gload16(Wg + (size_t)(d0 + r) * KDIM + k0 + cs * 4,              \
                    &wl[buf][(w * 16 + i * 4) * BK]);                        \
        }                                                                    \
        {                                                                    \
            const int cs = xch ^ (xrow & 7);                                 \
            gload16(Xb + (size_t)xrow * KDIM + k0 + cs * 8,                  \
                    &xl[buf][(w * 8) * BK]);                                 \
        }                                                                    \
    }

#define COMPUTE(buf)                                                         \
    {                                                                        \
        _Pragma("unroll")                                                    \
        for (int kk = 0; kk < 2; ++kk) {                                     \
            const int R  = w * 16 + (lane & 15);                             \
            const int c0 = kk * 8 + (lane >> 4) * 2;  /* 4-f32 chunk idx */  \
            const float4 f0 = *reinterpret_cast<const float4*>(              \
                &wl[buf][R * BK + ((c0    ) ^ (lane & 7)) * 4]);             \
            const float4 f1 = *reinterpret_cast<const float4*>(              \
                &wl[buf][R * BK + ((c0 + 1) ^ (lane & 7)) * 4]);             \
            short8 a;                                                        \
            a[0] = (short)bf16rne(f0.x); a[1] = (short)bf16rne(f0.y);        \
            a[2] = (short)bf16rne(f0.z); a[3] = (short)bf16rne(f0.w);        \
            a[4] = (short)bf16rne(f1.x); a[5] = (short)bf16rne(f1.y);        \
            a[6] = (short)bf16rne(f1.z); a[7] = (short)bf16rne(f1.w);        \
            _Pragma("unroll")                                                \
            for (int nt = 0; nt < 2; ++nt) {                                 \
                const int b  = nt * 16 + (lane & 15);                        \
                const int xc = (kk * 4 + (lane >> 4)) ^ (b & 7);             \
                const short8 bb = *reinterpret_cast<const short8*>(          \
                    &xl[buf][b * BK + xc * 8]);                              \
                acc[nt] = __builtin_amdgcn_mfma_f32_16x16x32_bf16(           \
                    a, bb, acc[nt], 0, 0, 0);                                \
            }                                                                \
        }                                                                    \
    }

    // prologue: two tiles in flight
    STAGE(0, 0)
    STAGE(1, 1)
    for (int tile = 0; tile < NTILE; ++tile) {
        const int cur = tile & 1;
        // wait current tile's 5 loads; keep next tile's 5 in flight
        if (tile + 1 < NTILE) {
            asm volatile("s_waitcnt vmcnt(5)" ::: "memory");
        } else {
            asm volatile("s_waitcnt vmcnt(0)" ::: "memory");
        }
        __builtin_amdgcn_s_barrier();          // all waves' quarters landed
        asm volatile("" ::: "memory");
        COMPUTE(cur)
        asm volatile("s_waitcnt lgkmcnt(0)" ::: "memory");  // LDS reads retired
        __builtin_amdgcn_s_barrier();          // safe to overwrite cur
        asm volatile("" ::: "memory");
        if (tile + 2 < NTILE) STAGE(cur, tile + 2)   // before waiting on t+1
    }
#undef STAGE
#undef COMPUTE

    // epilogue: D layout col=lane&15 (batch), row=(lane>>4)*4+reg (d)
    float* xp = xpart + (size_t)blockIdx.y * BATCH * DDIM;
#pragma unroll
    for (int nt = 0; nt < 2; ++nt) {
        const int b = nt * 16 + (lane & 15);
        const int m = d0 + w * 16 + (lane >> 4) * 4;
#pragma unroll
        for (int r = 0; r < 4; ++r)
            xp[(size_t)b * DDIM + m + r] = acc[nt][r];
    }
}

// ---------------- segment aggregation: one block per (image, channel) ------
template<int KSPLIT>
__global__ __launch_bounds__(256) void aggregate_kernel(
    const float* __restrict__ xpart, const float* __restrict__ bias,
    const int* __restrict__ seg, float* __restrict__ out)
{
    __shared__ float sums[NSEG];
    __shared__ int   hist[NSEG];
    const int b = blockIdx.x / CH;
    const int c = blockIdx.x % CH;
    for (int i = threadIdx.x; i < NSEG; i += 256) { sums[i] = 0.f; hist[i] = 0; }
    __syncthreads();
    const size_t base = (size_t)b * DDIM + c * HWPIX;
#pragma unroll
    for (int it = 0; it < HWPIX / 1024; ++it) {
        const int p0 = it * 1024 + threadIdx.x * 4;
        const int4 s4 = *reinterpret_cast<const int4*>(seg + b * HWPIX + p0);
        float4 v = *reinterpret_cast<const float4*>(bias + c * HWPIX + p0);
#pragma unroll
        for (int ks = 0; ks < KSPLIT; ++ks) {
            const float4 xv = *reinterpret_cast<const float4*>(
                xpart + (size_t)ks * BATCH * DDIM + base + p0);
            v.x += xv.x; v.y += xv.y; v.z += xv.z; v.w += xv.w;
        }
        atomicAdd(&hist[s4.x], 1); atomicAdd(&sums[s4.x], v.x);
        atomicAdd(&hist[s4.y], 1); atomicAdd(&sums[s4.y], v.y);
        atomicAdd(&hist[s4.z], 1); atomicAdd(&sums[s4.z], v.z);
        atomicAdd(&hist[s4.w], 1); atomicAdd(&sums[s4.w], v.w);
    }
    __syncthreads();
    for (int s = threadIdx.x; s < NSEG; s += 256)
        out[(b * NSEG + s) * CH + c] = sums[s] / fmaxf((float)hist[s], 1.f);
}

extern "C" void kernel_launch(void* const* d_in, const int* in_sizes, int n_in,
                              void* d_out, int out_size, void* d_ws, size_t ws_size,
                              hipStream_t stream) {
    const float* X    = (const float*)d_in[0];
    const float* W    = (const float*)d_in[1];
    const float* bias = (const float*)d_in[2];
    const int*   seg  = (const int*)d_in[3];
    float* out = (float*)d_out;

    ushort* Xb    = (ushort*)d_ws;                         // [32][12288] bf16, 0.75 MB
    float*  xpart = (float*)(Xb + (size_t)BATCH * KDIM);   // [KSPLIT][32][12288]

    convert_x_kernel<<<BATCH * KDIM / (256 * 4), 256, 0, stream>>>(X, Xb);

    const size_t base_ws = (size_t)BATCH * KDIM * 2;
    const size_t part_ws = (size_t)BATCH * DDIM * 4;
    if (ws_size >= base_ws + 16 * part_ws) {
        // grid 192*16 = 3072 = 3 x (4 blocks/CU x 256 CU): zero dispatch tail
        dim3 grid(DDIM / ROWS, 16);
        gemm_kernel<16><<<grid, 256, 0, stream>>>(W, Xb, xpart);
        aggregate_kernel<16><<<BATCH * CH, 256, 0, stream>>>(xpart, bias, seg, out);
    } else if (ws_size >= base_ws + 8 * part_ws) {
        dim3 grid(DDIM / ROWS, 8);
        gemm_kernel<8><<<grid, 256, 0, stream>>>(W, Xb, xpart);
        aggregate_kernel<8><<<BATCH * CH, 256, 0, stream>>>(xpart, bias, seg, out);
    } else {
        dim3 grid(DDIM / ROWS, 4);
        gemm_kernel<4><<<grid, 256, 0, stream>>>(W, Xb, xpart);
        aggregate_kernel<4><<<BATCH * CH, 256, 0, stream>>>(xpart, bias, seg, out);
    }
}

// Round 8
// 134.802 us; speedup vs baseline: 1.0478x; 1.0478x over previous
//
#include <hip/hip_runtime.h>

// SuperPixelMeanEmbed: x = X@W.T + b (M=32, N=K=12288), then per-superpixel
// channel means. W = 604 MB f32 read once -> HBM floor ~92 us at the
// measured 6.6 TB/s streaming rate (lower with ~40% L3 hit, R1/R2 FETCH).
//
// R8: R7 falsified the dispatch-tail theory (KSPLIT=16 regressed; revert to
// 8). Recount showed the f32->bf16 conversion was co-limiting: hand-rolled
// integer RNE = ~144 VALU instrs/wave/tile (~6700 cyc/CU/tile-period vs
// 7650 HBM). Fix: native __float22bfloat162_rn -> v_cvt_pk_bf16_f32
// (1 instr per 2 elems), ~4x less conversion VALU. Pipeline skeleton
// (counted vmcnt(5) + raw barriers), swizzles, MFMA datapath unchanged.

#include <hip/hip_bf16.h>

typedef __attribute__((ext_vector_type(8))) short short8;
typedef __attribute__((ext_vector_type(4))) float f32x4;

namespace {
constexpr int BATCH = 32;
constexpr int CH    = 3;
constexpr int HWPIX = 4096;     // 64*64
constexpr int DDIM  = 12288;
constexpr int KDIM  = 12288;
constexpr int NSEG  = 196;

constexpr int ROWS = 64;        // d-rows per block (wave w owns rows w*16..+15)
constexpr int BK   = 64;        // k per LDS tile
}

// native packed f32x2 -> bf16x2 (v_cvt_pk_bf16_f32, RNE)
__device__ __forceinline__ unsigned pkbf16(float lo, float hi) {
    __hip_bfloat162 h = __float22bfloat162_rn(make_float2(lo, hi));
    union { __hip_bfloat162 h2; unsigned u; } c; c.h2 = h; return c.u;
}

__device__ __forceinline__ void gload16(const void* g, void* l) {
    __builtin_amdgcn_global_load_lds(
        (const __attribute__((address_space(1))) void*)g,
        (__attribute__((address_space(3))) void*)l, 16, 0, 0);
}

// ---------------- X f32 -> bf16, same [b][k] layout ----------------
__global__ __launch_bounds__(256) void convert_x_kernel(
    const float* __restrict__ X, ushort* __restrict__ Xb)
{
    const int i = (blockIdx.x * 256 + threadIdx.x) * 4;
    const float4 v = *reinterpret_cast<const float4*>(X + i);
    union { unsigned u[2]; ushort4 q; } o;
    o.u[0] = pkbf16(v.x, v.y);
    o.u[1] = pkbf16(v.z, v.w);
    *reinterpret_cast<ushort4*>(Xb + i) = o.q;
}

// ---------------- MFMA skinny GEMM, split-K ----------------
// grid = (DDIM/64, KSPLIT); block 256 = 4 waves. Wave w computes the
// 16(d) x 32(batch) output tile for rows d0+w*16..+15 over its k-range.
// LDS: W tile f32 [64r][64k] (16 KB) + X tile bf16 [32b][64k] (4 KB), x2 buf.
// Both staged by global_load_lds with pre-swizzled source chunks
// (chunk ^= row&7, 16B granules); reads XOR the same -> conflict-free.
template<int KSPLIT>
__global__ __launch_bounds__(256, 4) void gemm_kernel(
    const float* __restrict__ Wg, const ushort* __restrict__ Xb,
    float* __restrict__ xpart)
{
    constexpr int KRANGE = KDIM / KSPLIT;
    constexpr int NTILE  = KRANGE / BK;

    __shared__ float  wl[2][ROWS * BK];    // 2 x 16 KB
    __shared__ ushort xl[2][BATCH * BK];   // 2 x 4 KB

    const int t    = threadIdx.x;
    const int lane = t & 63;
    const int w    = t >> 6;
    const int d0   = blockIdx.x * ROWS;
    const int kb   = blockIdx.y * KRANGE;

    // staging geometry
    const int rsub = lane >> 4;            // W: sub-row within 4-row gload group
    const int cch  = lane & 15;            // W: 16B chunk slot (16 per 256B row)
    const int xrow = w * 8 + (lane >> 3);  // X: b-row (8 rows/wave, 128B each)
    const int xch  = lane & 7;             // X: 16B chunk slot (8 per row)

    f32x4 acc[2];
#pragma unroll
    for (int nt = 0; nt < 2; ++nt) acc[nt] = (f32x4)(0.f);

#define STAGE(buf, tile)                                                     \
    {                                                                        \
        const int k0 = kb + (tile) * BK;                                     \
        _Pragma("unroll")                                                    \
        for (int i = 0; i < 4; ++i) {                                        \
            const int r  = w * 16 + i * 4 + rsub;                            \
            const int cs = cch ^ (r & 7);                                    \
            gload16(Wg + (size_t)(d0 + r) * KDIM + k0 + cs * 4,              \
                    &wl[buf][(w * 16 + i * 4) * BK]);                        \
        }                                                                    \
        {                                                                    \
            const int cs = xch ^ (xrow & 7);                                 \
            gload16(Xb + (size_t)xrow * KDIM + k0 + cs * 8,                  \
                    &xl[buf][(w * 8) * BK]);                                 \
        }                                                                    \
    }

#define COMPUTE(buf)                                                         \
    {                                                                        \
        _Pragma("unroll")                                                    \
        for (int kk = 0; kk < 2; ++kk) {                                     \
            const int R  = w * 16 + (lane & 15);                             \
            const int c0 = kk * 8 + (lane >> 4) * 2;  /* 4-f32 chunk idx */  \
            const float4 f0 = *reinterpret_cast<const float4*>(              \
                &wl[buf][R * BK + ((c0    ) ^ (lane & 7)) * 4]);             \
            const float4 f1 = *reinterpret_cast<const float4*>(              \
                &wl[buf][R * BK + ((c0 + 1) ^ (lane & 7)) * 4]);             \
            union { unsigned u[4]; short8 s8; } A;                           \
            A.u[0] = pkbf16(f0.x, f0.y);                                     \
            A.u[1] = pkbf16(f0.z, f0.w);                                     \
            A.u[2] = pkbf16(f1.x, f1.y);                                     \
            A.u[3] = pkbf16(f1.z, f1.w);                                     \
            _Pragma("unroll")                                                \
            for (int nt = 0; nt < 2; ++nt) {                                 \
                const int b  = nt * 16 + (lane & 15);                        \
                const int xc = (kk * 4 + (lane >> 4)) ^ (b & 7);             \
                const short8 bb = *reinterpret_cast<const short8*>(          \
                    &xl[buf][b * BK + xc * 8]);                              \
                acc[nt] = __builtin_amdgcn_mfma_f32_16x16x32_bf16(           \
                    A.s8, bb, acc[nt], 0, 0, 0);                             \
            }                                                                \
        }                                                                    \
    }

    // prologue: two tiles in flight
    STAGE(0, 0)
    STAGE(1, 1)
    for (int tile = 0; tile < NTILE; ++tile) {
        const int cur = tile & 1;
        // wait current tile's 5 loads; keep next tile's 5 in flight
        if (tile + 1 < NTILE) {
            asm volatile("s_waitcnt vmcnt(5)" ::: "memory");
        } else {
            asm volatile("s_waitcnt vmcnt(0)" ::: "memory");
        }
        __builtin_amdgcn_s_barrier();          // all waves' quarters landed
        asm volatile("" ::: "memory");
        COMPUTE(cur)
        asm volatile("s_waitcnt lgkmcnt(0)" ::: "memory");  // LDS reads retired
        __builtin_amdgcn_s_barrier();          // safe to overwrite cur
        asm volatile("" ::: "memory");
        if (tile + 2 < NTILE) STAGE(cur, tile + 2)   // before waiting on t+1
    }
#undef STAGE
#undef COMPUTE

    // epilogue: D layout col=lane&15 (batch), row=(lane>>4)*4+reg (d)
    float* xp = xpart + (size_t)blockIdx.y * BATCH * DDIM;
#pragma unroll
    for (int nt = 0; nt < 2; ++nt) {
        const int b = nt * 16 + (lane & 15);
        const int m = d0 + w * 16 + (lane >> 4) * 4;
#pragma unroll
        for (int r = 0; r < 4; ++r)
            xp[(size_t)b * DDIM + m + r] = acc[nt][r];
    }
}

// ---------------- segment aggregation: one block per (image, channel) ------
template<int KSPLIT>
__global__ __launch_bounds__(256) void aggregate_kernel(
    const float* __restrict__ xpart, const float* __restrict__ bias,
    const int* __restrict__ seg, float* __restrict__ out)
{
    __shared__ float sums[NSEG];
    __shared__ int   hist[NSEG];
    const int b = blockIdx.x / CH;
    const int c = blockIdx.x % CH;
    for (int i = threadIdx.x; i < NSEG; i += 256) { sums[i] = 0.f; hist[i] = 0; }
    __syncthreads();
    const size_t base = (size_t)b * DDIM + c * HWPIX;
#pragma unroll
    for (int it = 0; it < HWPIX / 1024; ++it) {
        const int p0 = it * 1024 + threadIdx.x * 4;
        const int4 s4 = *reinterpret_cast<const int4*>(seg + b * HWPIX + p0);
        float4 v = *reinterpret_cast<const float4*>(bias + c * HWPIX + p0);
#pragma unroll
        for (int ks = 0; ks < KSPLIT; ++ks) {
            const float4 xv = *reinterpret_cast<const float4*>(
                xpart + (size_t)ks * BATCH * DDIM + base + p0);
            v.x += xv.x; v.y += xv.y; v.z += xv.z; v.w += xv.w;
        }
        atomicAdd(&hist[s4.x], 1); atomicAdd(&sums[s4.x], v.x);
        atomicAdd(&hist[s4.y], 1); atomicAdd(&sums[s4.y], v.y);
        atomicAdd(&hist[s4.z], 1); atomicAdd(&sums[s4.z], v.z);
        atomicAdd(&hist[s4.w], 1); atomicAdd(&sums[s4.w], v.w);
    }
    __syncthreads();
    for (int s = threadIdx.x; s < NSEG; s += 256)
        out[(b * NSEG + s) * CH + c] = sums[s] / fmaxf((float)hist[s], 1.f);
}

extern "C" void kernel_launch(void* const* d_in, const int* in_sizes, int n_in,
                              void* d_out, int out_size, void* d_ws, size_t ws_size,
                              hipStream_t stream) {
    const float* X    = (const float*)d_in[0];
    const float* W    = (const float*)d_in[1];
    const float* bias = (const float*)d_in[2];
    const int*   seg  = (const int*)d_in[3];
    float* out = (float*)d_out;

    ushort* Xb    = (ushort*)d_ws;                         // [32][12288] bf16, 0.75 MB
    float*  xpart = (float*)(Xb + (size_t)BATCH * KDIM);   // [KSPLIT][32][12288]

    convert_x_kernel<<<BATCH * KDIM / (256 * 4), 256, 0, stream>>>(X, Xb);

    const size_t base_ws = (size_t)BATCH * KDIM * 2;
    const size_t part_ws = (size_t)BATCH * DDIM * 4;
    if (ws_size >= base_ws + 8 * part_ws) {
        dim3 grid(DDIM / ROWS, 8);
        gemm_kernel<8><<<grid, 256, 0, stream>>>(W, Xb, xpart);
        aggregate_kernel<8><<<BATCH * CH, 256, 0, stream>>>(xpart, bias, seg, out);
    } else {
        dim3 grid(DDIM / ROWS, 4);
        gemm_kernel<4><<<grid, 256, 0, stream>>>(W, Xb, xpart);
        aggregate_kernel<4><<<BATCH * CH, 256, 0, stream>>>(xpart, bias, seg, out);
    }
}

// Round 9
// 133.473 us; speedup vs baseline: 1.0582x; 1.0100x over previous
//
#include <hip/hip_runtime.h>

// SuperPixelMeanEmbed: x = X@W.T + b (M=32, N=K=12288), then per-superpixel
// channel means. W = 604 MB f32 read once.
//
// R9: gemm pinned at ~5.1 TB/s vs 6.6 TB/s fill rate; VALU/pipeline/tail all
// falsified. Surviving theory: DRAM page fragmentation -- 256 B per row per
// tile across ~65K concurrent streams defeats page coalescing. Fix: BK=128
// (512 B/row/tile), 80 KB LDS, 2 blocks/CU, grid 1536 = 3 exact waves,
// counted vmcnt(10). Swizzle/MFMA datapath/aggregation unchanged.

#include <hip/hip_bf16.h>

typedef __attribute__((ext_vector_type(8))) short short8;
typedef __attribute__((ext_vector_type(4))) float f32x4;

namespace {
constexpr int BATCH = 32;
constexpr int CH    = 3;
constexpr int HWPIX = 4096;     // 64*64
constexpr int DDIM  = 12288;
constexpr int KDIM  = 12288;
constexpr int NSEG  = 196;

constexpr int ROWS = 64;        // d-rows per block (wave w owns rows w*16..+15)
constexpr int BK   = 128;       // k per LDS tile (512 B per W row per tile)
}

// native packed f32x2 -> bf16x2 (v_cvt_pk_bf16_f32, RNE)
__device__ __forceinline__ unsigned pkbf16(float lo, float hi) {
    __hip_bfloat162 h = __float22bfloat162_rn(make_float2(lo, hi));
    union { __hip_bfloat162 h2; unsigned u; } c; c.h2 = h; return c.u;
}

__device__ __forceinline__ void gload16(const void* g, void* l) {
    __builtin_amdgcn_global_load_lds(
        (const __attribute__((address_space(1))) void*)g,
        (__attribute__((address_space(3))) void*)l, 16, 0, 0);
}

// ---------------- X f32 -> bf16, same [b][k] layout ----------------
__global__ __launch_bounds__(256) void convert_x_kernel(
    const float* __restrict__ X, ushort* __restrict__ Xb)
{
    const int i = (blockIdx.x * 256 + threadIdx.x) * 4;
    const float4 v = *reinterpret_cast<const float4*>(X + i);
    union { unsigned u[2]; ushort4 q; } o;
    o.u[0] = pkbf16(v.x, v.y);
    o.u[1] = pkbf16(v.z, v.w);
    *reinterpret_cast<ushort4*>(Xb + i) = o.q;
}

// ---------------- MFMA skinny GEMM, split-K ----------------
// grid = (DDIM/64, KSPLIT); block 256 = 4 waves. Wave w computes the
// 16(d) x 32(batch) output tile for rows d0+w*16..+15 over its k-range.
// LDS: W tile f32 [64r][128k] (32 KB) + X tile bf16 [32b][128k] (8 KB), x2.
// Both staged by global_load_lds with pre-swizzled source chunks
// (16B chunk slot = chunk ^ (row&7)); reads XOR the same -> conflict-free
// (residual 2-way aliasing is free).
template<int KSPLIT>
__global__ __launch_bounds__(256, 2) void gemm_kernel(
    const float* __restrict__ Wg, const ushort* __restrict__ Xb,
    float* __restrict__ xpart)
{
    constexpr int KRANGE = KDIM / KSPLIT;
    constexpr int NTILE  = KRANGE / BK;

    __shared__ float  wl[2][ROWS * BK];    // 2 x 32 KB
    __shared__ ushort xl[2][BATCH * BK];   // 2 x 8 KB

    const int t    = threadIdx.x;
    const int lane = t & 63;
    const int w    = t >> 6;
    const int d0   = blockIdx.x * ROWS;
    const int kb   = blockIdx.y * KRANGE;

    f32x4 acc[2];
#pragma unroll
    for (int nt = 0; nt < 2; ++nt) acc[nt] = (f32x4)(0.f);

    // W staging: 8 instrs/wave; instr i covers rows w*16+i*2+(lane>>5),
    // 32 chunk slots (512 B) per row. X staging: 2 instrs/wave; instr i
    // covers rows w*8+i*4+(lane>>4), 16 chunk slots (256 B) per row.
#define STAGE(buf, tile)                                                     \
    {                                                                        \
        const int k0 = kb + (tile) * BK;                                     \
        _Pragma("unroll")                                                    \
        for (int i = 0; i < 8; ++i) {                                        \
            const int r  = w * 16 + i * 2 + (lane >> 5);                     \
            const int cs = (lane & 31) ^ (r & 7);                            \
            gload16(Wg + (size_t)(d0 + r) * KDIM + k0 + cs * 4,              \
                    &wl[buf][(w * 16 + i * 2) * BK]);                        \
        }                                                                    \
        _Pragma("unroll")                                                    \
        for (int i = 0; i < 2; ++i) {                                        \
            const int xr = w * 8 + i * 4 + (lane >> 4);                      \
            const int cs = (lane & 15) ^ (xr & 7);                           \
            gload16(Xb + (size_t)xr * KDIM + k0 + cs * 8,                    \
                    &xl[buf][(w * 8 + i * 4) * BK]);                         \
        }                                                                    \
    }

#define COMPUTE(buf)                                                         \
    {                                                                        \
        _Pragma("unroll")                                                    \
        for (int kk = 0; kk < 4; ++kk) {                                     \
            const int R  = w * 16 + (lane & 15);                             \
            const int c0 = kk * 8 + (lane >> 4) * 2;  /* 16B chunk idx */    \
            const float4 f0 = *reinterpret_cast<const float4*>(              \
                &wl[buf][R * BK + (((c0    ) ^ (R & 7)) & 31) * 4]);         \
            const float4 f1 = *reinterpret_cast<const float4*>(              \
                &wl[buf][R * BK + (((c0 + 1) ^ (R & 7)) & 31) * 4]);         \
            union { unsigned u[4]; short8 s8; } A;                           \
            A.u[0] = pkbf16(f0.x, f0.y);                                     \
            A.u[1] = pkbf16(f0.z, f0.w);                                     \
            A.u[2] = pkbf16(f1.x, f1.y);                                     \
            A.u[3] = pkbf16(f1.z, f1.w);                                     \
            _Pragma("unroll")                                                \
            for (int nt = 0; nt < 2; ++nt) {                                 \
                const int b  = nt * 16 + (lane & 15);                        \
                const int xc = (kk * 4 + (lane >> 4)) ^ (b & 7);             \
                const short8 bb = *reinterpret_cast<const short8*>(          \
                    &xl[buf][b * BK + xc * 8]);                              \
                acc[nt] = __builtin_amdgcn_mfma_f32_16x16x32_bf16(           \
                    A.s8, bb, acc[nt], 0, 0, 0);                             \
            }                                                                \
        }                                                                    \
    }

    // prologue: two tiles (2 x 10 instrs/wave) in flight
    STAGE(0, 0)
    STAGE(1, 1)
    for (int tile = 0; tile < NTILE; ++tile) {
        const int cur = tile & 1;
        // wait current tile's 10 loads; keep next tile's 10 in flight
        if (tile + 1 < NTILE) {
            asm volatile("s_waitcnt vmcnt(10)" ::: "memory");
        } else {
            asm volatile("s_waitcnt vmcnt(0)" ::: "memory");
        }
        __builtin_amdgcn_s_barrier();          // all waves' quarters landed
        asm volatile("" ::: "memory");
        COMPUTE(cur)
        asm volatile("s_waitcnt lgkmcnt(0)" ::: "memory");  // LDS reads retired
        __builtin_amdgcn_s_barrier();          // safe to overwrite cur
        asm volatile("" ::: "memory");
        if (tile + 2 < NTILE) STAGE(cur, tile + 2)   // before waiting on t+1
    }
#undef STAGE
#undef COMPUTE

    // epilogue: D layout col=lane&15 (batch), row=(lane>>4)*4+reg (d)
    float* xp = xpart + (size_t)blockIdx.y * BATCH * DDIM;
#pragma unroll
    for (int nt = 0; nt < 2; ++nt) {
        const int b = nt * 16 + (lane & 15);
        const int m = d0 + w * 16 + (lane >> 4) * 4;
#pragma unroll
        for (int r = 0; r < 4; ++r)
            xp[(size_t)b * DDIM + m + r] = acc[nt][r];
    }
}

// ---------------- segment aggregation: one block per (image, channel) ------
template<int KSPLIT>
__global__ __launch_bounds__(256) void aggregate_kernel(
    const float* __restrict__ xpart, const float* __restrict__ bias,
    const int* __restrict__ seg, float* __restrict__ out)
{
    __shared__ float sums[NSEG];
    __shared__ int   hist[NSEG];
    const int b = blockIdx.x / CH;
    const int c = blockIdx.x % CH;
    for (int i = threadIdx.x; i < NSEG; i += 256) { sums[i] = 0.f; hist[i] = 0; }
    __syncthreads();
    const size_t base = (size_t)b * DDIM + c * HWPIX;
#pragma unroll
    for (int it = 0; it < HWPIX / 1024; ++it) {
        const int p0 = it * 1024 + threadIdx.x * 4;
        const int4 s4 = *reinterpret_cast<const int4*>(seg + b * HWPIX + p0);
        float4 v = *reinterpret_cast<const float4*>(bias + c * HWPIX + p0);
#pragma unroll
        for (int ks = 0; ks < KSPLIT; ++ks) {
            const float4 xv = *reinterpret_cast<const float4*>(
                xpart + (size_t)ks * BATCH * DDIM + base + p0);
            v.x += xv.x; v.y += xv.y; v.z += xv.z; v.w += xv.w;
        }
        atomicAdd(&hist[s4.x], 1); atomicAdd(&sums[s4.x], v.x);
        atomicAdd(&hist[s4.y], 1); atomicAdd(&sums[s4.y], v.y);
        atomicAdd(&hist[s4.z], 1); atomicAdd(&sums[s4.z], v.z);
        atomicAdd(&hist[s4.w], 1); atomicAdd(&sums[s4.w], v.w);
    }
    __syncthreads();
    for (int s = threadIdx.x; s < NSEG; s += 256)
        out[(b * NSEG + s) * CH + c] = sums[s] / fmaxf((float)hist[s], 1.f);
}

extern "C" void kernel_launch(void* const* d_in, const int* in_sizes, int n_in,
                              void* d_out, int out_size, void* d_ws, size_t ws_size,
                              hipStream_t stream) {
    const float* X    = (const float*)d_in[0];
    const float* W    = (const float*)d_in[1];
    const float* bias = (const float*)d_in[2];
    const int*   seg  = (const int*)d_in[3];
    float* out = (float*)d_out;

    ushort* Xb    = (ushort*)d_ws;                         // [32][12288] bf16, 0.75 MB
    float*  xpart = (float*)(Xb + (size_t)BATCH * KDIM);   // [KSPLIT][32][12288]

    convert_x_kernel<<<BATCH * KDIM / (256 * 4), 256, 0, stream>>>(X, Xb);

    const size_t base_ws = (size_t)BATCH * KDIM * 2;
    const size_t part_ws = (size_t)BATCH * DDIM * 4;
    if (ws_size >= base_ws + 8 * part_ws) {
        // grid 192*8 = 1536 = 3 x (2 blocks/CU x 256 CU): zero dispatch tail
        dim3 grid(DDIM / ROWS, 8);
        gemm_kernel<8><<<grid, 256, 0, stream>>>(W, Xb, xpart);
        aggregate_kernel<8><<<BATCH * CH, 256, 0, stream>>>(xpart, bias, seg, out);
    } else {
        dim3 grid(DDIM / ROWS, 4);
        gemm_kernel<4><<<grid, 256, 0, stream>>>(W, Xb, xpart);
        aggregate_kernel<4><<<BATCH * CH, 256, 0, stream>>>(xpart, bias, seg, out);
    }
}